// Round 1
// baseline (64.734 us; speedup 1.0000x reference)
//
#include <hip/hip_runtime.h>

#define NUM_EXPERTS 64
#define CAPACITY    320
#define NUM_TOKENS  16384
#define EMBED_DIM   2048
#define CHUNK       256
#define NUM_CHUNKS  (NUM_TOKENS / CHUNK)   // 64

// ---------------------------------------------------------------------------
// ws layout (ints):
//   [0                 .. 4096)  counts[chunk][expert]
//   [4096              .. 8192)  offsets[chunk][expert]   (exclusive scan over chunks, per expert)
//   [8192              .. 28672) slot_token[NUM_EXPERTS*CAPACITY]
// ---------------------------------------------------------------------------

__global__ void k_init(int* __restrict__ slot_token,
                       float* __restrict__ out_combine,
                       float* __restrict__ out_tokidx) {
    int i = blockIdx.x * blockDim.x + threadIdx.x;
    if (i < NUM_EXPERTS * CAPACITY) {
        slot_token[i]  = -1;
        out_combine[i] = 0.0f;
        out_tokidx[i]  = -1.0f;
    }
}

__global__ void k_hist(const int* __restrict__ expert_ids,
                       int* __restrict__ counts) {
    __shared__ int h[NUM_EXPERTS];
    int t = threadIdx.x;
    if (t < NUM_EXPERTS) h[t] = 0;
    __syncthreads();
    int tok = blockIdx.x * CHUNK + t;
    int e = expert_ids[tok];
    atomicAdd(&h[e], 1);
    __syncthreads();
    if (t < NUM_EXPERTS) counts[blockIdx.x * NUM_EXPERTS + t] = h[t];
}

// one wave of 64 threads: thread e scans expert e across chunks (token order),
// then wave-reduce the per-expert overflow into tokens_dropped.
__global__ void k_scan(const int* __restrict__ counts,
                       int* __restrict__ offsets,
                       float* __restrict__ out_dropped) {
    int e = threadIdx.x;       // 0..63
    int run = 0;
    for (int b = 0; b < NUM_CHUNKS; ++b) {
        offsets[b * NUM_EXPERTS + e] = run;
        run += counts[b * NUM_EXPERTS + e];
    }
    int dropped = run > CAPACITY ? run - CAPACITY : 0;
    #pragma unroll
    for (int off = 32; off > 0; off >>= 1)
        dropped += __shfl_down(dropped, off);
    if (e == 0) out_dropped[0] = (float)dropped;
}

__global__ void k_scatter(const int* __restrict__ expert_ids,
                          const float* __restrict__ weights,
                          const int* __restrict__ offsets,
                          int* __restrict__ slot_token,
                          float* __restrict__ out_combine,
                          float* __restrict__ out_tokidx) {
    __shared__ int eids[CHUNK];
    int t = threadIdx.x;
    int tok = blockIdx.x * CHUNK + t;
    int e = expert_ids[tok];
    eids[t] = e;
    __syncthreads();
    // stable within-chunk rank among same-expert tokens (token order)
    int rank = 0;
    for (int j = 0; j < t; ++j) rank += (eids[j] == e);
    int pos = offsets[blockIdx.x * NUM_EXPERTS + e] + rank;
    if (pos < CAPACITY) {
        int slot = e * CAPACITY + pos;
        slot_token[slot]  = tok;
        out_combine[slot] = weights[tok];
        out_tokidx[slot]  = (float)tok;
    }
}

// one block per (expert,slot): write every dispatched_x element exactly once.
__global__ void k_gather(const float* __restrict__ x,
                         const int* __restrict__ slot_token,
                         float* __restrict__ out_x) {
    int slot = blockIdx.x;
    int tok  = slot_token[slot];
    float4* dst = (float4*)(out_x + (size_t)slot * EMBED_DIM);
    int t = threadIdx.x;               // 256 threads, 2 float4 each (512 f4 total)
    if (tok >= 0) {
        const float4* src = (const float4*)(x + (size_t)tok * EMBED_DIM);
        dst[t]       = src[t];
        dst[t + 256] = src[t + 256];
    } else {
        float4 z = make_float4(0.f, 0.f, 0.f, 0.f);
        dst[t]       = z;
        dst[t + 256] = z;
    }
}

extern "C" void kernel_launch(void* const* d_in, const int* in_sizes, int n_in,
                              void* d_out, int out_size, void* d_ws, size_t ws_size,
                              hipStream_t stream) {
    const float* x          = (const float*)d_in[0];
    const int*   expert_ids = (const int*)d_in[1];
    const float* weights    = (const float*)d_in[2];

    float* out         = (float*)d_out;
    float* out_x       = out;
    float* out_combine = out + (size_t)NUM_EXPERTS * CAPACITY * EMBED_DIM;
    float* out_tokidx  = out_combine + NUM_EXPERTS * CAPACITY;
    float* out_dropped = out_tokidx  + NUM_EXPERTS * CAPACITY;

    int* counts     = (int*)d_ws;
    int* offsets    = counts  + NUM_CHUNKS * NUM_EXPERTS;
    int* slot_token = offsets + NUM_CHUNKS * NUM_EXPERTS;

    k_init<<<(NUM_EXPERTS * CAPACITY + 255) / 256, 256, 0, stream>>>(
        slot_token, out_combine, out_tokidx);
    k_hist<<<NUM_CHUNKS, CHUNK, 0, stream>>>(expert_ids, counts);
    k_scan<<<1, 64, 0, stream>>>(counts, offsets, out_dropped);
    k_scatter<<<NUM_CHUNKS, CHUNK, 0, stream>>>(
        expert_ids, weights, offsets, slot_token, out_combine, out_tokidx);
    k_gather<<<NUM_EXPERTS * CAPACITY, 256, 0, stream>>>(x, slot_token, out_x);
}